// Round 2
// baseline (9881.004 us; speedup 1.0000x reference)
//
#include <hip/hip_runtime.h>
#include <hip/hip_bf16.h>
#include <cstdint>

typedef __bf16 bf16_t;
typedef __bf16 bf16x8 __attribute__((ext_vector_type(8)));
typedef float  f32x4  __attribute__((ext_vector_type(4)));

#define T_SEQ 512
#define NWG   256

// ---------------- gather + convert: xe[t*64+b][512] = bf16(emb[x[b,t]]) ----------------
__global__ void gather_xe(const int* __restrict__ x, const float* __restrict__ emb,
                          bf16_t* __restrict__ xe) {
  const int row = blockIdx.x;            // row = t*64 + b
  const int b = row & 63, t = row >> 6;
  const int tok = x[b * 512 + t];        // x is [B][T]
  const float4* src = (const float4*)(emb + (size_t)tok * 512);
  float4 a = src[threadIdx.x * 2], c = src[threadIdx.x * 2 + 1];
  bf16x8 v;
  v[0] = (bf16_t)a.x; v[1] = (bf16_t)a.y; v[2] = (bf16_t)a.z; v[3] = (bf16_t)a.w;
  v[4] = (bf16_t)c.x; v[5] = (bf16_t)c.y; v[6] = (bf16_t)c.z; v[7] = (bf16_t)c.w;
  *(bf16x8*)(xe + (size_t)row * 512 + threadIdx.x * 8) = v;
}

// ---------------- persistent sequential LSTM (cooperative launch) ----------------
// WG wg owns h-columns wg*4..wg*4+3 -> 16 weight rows (4 gates x 4 cols) of both
// W_ih (K=512) and W_hh (K=1024), LDS-resident in bf16.
// Per step: gates = xe[t]@Wih_slice^T (pre-barrier) + h@Whh_slice^T (post-barrier).
// h double-buffered in global bf16 [2][64][1024]; flag-per-WG monotonic barrier.
__global__ __launch_bounds__(256, 1) void lstm_seq(
    const bf16_t* __restrict__ xe,       // [512*64][512]
    const float* __restrict__ wih,       // [4096][512]
    const float* __restrict__ whh,       // [4096][1024]
    const float* __restrict__ bih, const float* __restrict__ bhh,
    const float* __restrict__ wfc, const float* __restrict__ bfc,
    bf16_t* __restrict__ hb,             // [2][64][1024]
    int* __restrict__ flags,             // [NWG]
    float* __restrict__ out) {
  __shared__ bf16_t whh_s[16][1032];     // 16 rows x (1024 + 8 pad)
  __shared__ bf16_t wih_s[16][520];      // 16 rows x (512 + 8 pad)
  __shared__ float gates_s[64][17];
  const int tid = threadIdx.x, wg = blockIdx.x;
  const int lane = tid & 63, w = tid >> 6;

  // load weight slices f32 -> bf16; local row r = gate*4+j <-> global row gate*1024 + wg*4 + j
  {
    const int r = tid >> 4;
    const int gate = r >> 2, j = r & 2 ? (r & 3) : (r & 3); // r & 3
    const int grow = gate * 1024 + wg * 4 + (r & 3);
    {
      const int ch = (tid & 15) << 6;    // 64 f32 each
      const float* src = whh + (size_t)grow * 1024 + ch;
      bf16_t* dst = &whh_s[r][ch];
#pragma unroll 8
      for (int u = 0; u < 64; ++u) dst[u] = (bf16_t)src[u];
    }
    {
      const int ch = (tid & 15) << 5;    // 32 f32 each
      const float* src = wih + (size_t)grow * 512 + ch;
      bf16_t* dst = &wih_s[r][ch];
#pragma unroll 8
      for (int u = 0; u < 32; ++u) dst[u] = (bf16_t)src[u];
    }
  }
  // zero h[0] cooperatively (256 WG x 256 thr == 65536 elems)
  hb[wg * 256 + tid] = (bf16_t)0.f;
  __syncthreads();
  if (tid == 0) {
    __builtin_amdgcn_fence(__ATOMIC_RELEASE, "agent");
    __hip_atomic_store(flags + wg, 1, __ATOMIC_RELAXED, __HIP_MEMORY_SCOPE_AGENT);
  }

  // per-thread elementwise ownership and biases
  const int bth = tid >> 2, jth = tid & 3;
  const int col = wg * 4 + jth;
  const float bi = bih[0 * 1024 + col] + bhh[0 * 1024 + col];
  const float bf_ = bih[1 * 1024 + col] + bhh[1 * 1024 + col];
  const float bg = bih[2 * 1024 + col] + bhh[2 * 1024 + col];
  const float bo = bih[3 * 1024 + col] + bhh[3 * 1024 + col];

  float c = 0.f;
  const int b0 = w << 4;                 // wave's 16-batch tile
  const int rloc = lane & 15, kg = lane >> 4;

  for (int t = 0; t < T_SEQ; ++t) {
    const bf16_t* hcur = hb + (size_t)(t & 1) * 65536;
    bf16_t* hnext = hb + (size_t)((t + 1) & 1) * 65536;

    // ---- xp part: gates += xe[t] @ Wih_slice^T  (no h dependency) ----
    f32x4 acc0 = {0.f, 0.f, 0.f, 0.f}, acc1 = {0.f, 0.f, 0.f, 0.f};
    {
      const bf16_t* ar = xe + ((size_t)t * 64 + b0 + rloc) * 512 + (kg << 3);
      const bf16_t* br = &wih_s[rloc][kg << 3];
#pragma unroll
      for (int kk = 0; kk < 16; kk += 2) {
        acc0 = __builtin_amdgcn_mfma_f32_16x16x32_bf16(
            *(const bf16x8*)(ar + kk * 32), *(const bf16x8*)(br + kk * 32), acc0, 0, 0, 0);
        acc1 = __builtin_amdgcn_mfma_f32_16x16x32_bf16(
            *(const bf16x8*)(ar + kk * 32 + 32), *(const bf16x8*)(br + kk * 32 + 32), acc1, 0, 0, 0);
      }
    }

    // ---- wait for h(t) ready from all WGs ----
    {
      const int tgt = t + 1;
      while (__hip_atomic_load(flags + tid, __ATOMIC_RELAXED, __HIP_MEMORY_SCOPE_AGENT) < tgt)
        __builtin_amdgcn_s_sleep(1);
      __syncthreads();
      __builtin_amdgcn_fence(__ATOMIC_ACQUIRE, "agent");
    }

    // ---- h part: gates += h @ Whh_slice^T ----
    {
      const bf16_t* ar = hcur + (size_t)(b0 + rloc) * 1024 + (kg << 3);
      const bf16_t* br = &whh_s[rloc][kg << 3];
#pragma unroll
      for (int kk = 0; kk < 32; kk += 2) {
        acc0 = __builtin_amdgcn_mfma_f32_16x16x32_bf16(
            *(const bf16x8*)(ar + kk * 32), *(const bf16x8*)(br + kk * 32), acc0, 0, 0, 0);
        acc1 = __builtin_amdgcn_mfma_f32_16x16x32_bf16(
            *(const bf16x8*)(ar + kk * 32 + 32), *(const bf16x8*)(br + kk * 32 + 32), acc1, 0, 0, 0);
      }
    }
    f32x4 accs = acc0 + acc1;
    // D row m=kg*4+r -> batch b0+m, col rloc -> local gate row
#pragma unroll
    for (int r = 0; r < 4; ++r) gates_s[b0 + kg * 4 + r][rloc] = accs[r];
    __syncthreads();

    // ---- elementwise: thread (bth, jth) ----
    const float gi = gates_s[bth][0 + jth] + bi;
    const float gf = gates_s[bth][4 + jth] + bf_;
    const float gg = gates_s[bth][8 + jth] + bg;
    const float go = gates_s[bth][12 + jth] + bo;
    const float ii = 1.f / (1.f + __expf(-gi));
    const float ff = 1.f / (1.f + __expf(-gf));
    const float gv = tanhf(gg);
    const float oo = 1.f / (1.f + __expf(-go));
    c = ff * c + ii * gv;
    const float hv = oo * tanhf(c);
    hnext[(size_t)bth * 1024 + col] = (bf16_t)hv;
    __syncthreads();   // hnext stores done (vmcnt drained per-thread) + gates_s consumed

    if (tid == 0) {
      __builtin_amdgcn_fence(__ATOMIC_RELEASE, "agent");
      __hip_atomic_store(flags + wg, t + 2, __ATOMIC_RELAXED, __HIP_MEMORY_SCOPE_AGENT);
    }
  }

  // ---- final FC + sigmoid on WG 0 (final h is hb[0] after 512 steps) ----
  if (wg != 0) return;
  while (__hip_atomic_load(flags + tid, __ATOMIC_RELAXED, __HIP_MEMORY_SCOPE_AGENT) < T_SEQ + 1)
    __builtin_amdgcn_s_sleep(1);
  __syncthreads();
  __builtin_amdgcn_fence(__ATOMIC_ACQUIRE, "agent");

  const int bb = tid >> 2, part = tid & 3;
  const bf16_t* hrow = hb + (size_t)bb * 1024 + part * 256;
  const float* wrow = wfc + part * 256;
  float s = 0.f;
  for (int k = 0; k < 256; ++k) s += (float)hrow[k] * wrow[k];
  s += __shfl_xor(s, 1);
  s += __shfl_xor(s, 2);
  if (part == 0) out[bb] = 1.f / (1.f + __expf(-(s + bfc[0])));
}

extern "C" void kernel_launch(void* const* d_in, const int* in_sizes, int n_in,
                              void* d_out, int out_size, void* d_ws, size_t ws_size,
                              hipStream_t stream) {
  const int* x = (const int*)d_in[0];
  const float* emb = (const float*)d_in[1];
  const float* wih = (const float*)d_in[2];
  const float* whh = (const float*)d_in[3];
  const float* bih = (const float*)d_in[4];
  const float* bhh = (const float*)d_in[5];
  const float* wfc = (const float*)d_in[6];
  const float* bfc = (const float*)d_in[7];
  float* out = (float*)d_out;

  char* ws = (char*)d_ws;
  bf16_t* xe = (bf16_t*)ws;                          // 33,554,432 B
  bf16_t* hb = (bf16_t*)(ws + 33554432);             //    262,144 B
  int* flags = (int*)(ws + 33554432 + 262144);       //      1,024 B

  hipMemsetAsync(flags, 0, NWG * sizeof(int), stream);
  gather_xe<<<32768, 64, 0, stream>>>(x, emb, xe);

  void* args[] = {(void*)&xe, (void*)&wih, (void*)&whh, (void*)&bih, (void*)&bhh,
                  (void*)&wfc, (void*)&bfc, (void*)&hb, (void*)&flags, (void*)&out};
  hipLaunchCooperativeKernel((const void*)lstm_seq, dim3(NWG), dim3(256), args, 0, stream);
}

// Round 3
// 5657.518 us; speedup vs baseline: 1.7465x; 1.7465x over previous
//
#include <hip/hip_runtime.h>
#include <hip/hip_bf16.h>
#include <cstdint>

typedef __bf16 bf16_t;
typedef __bf16 bf16x8 __attribute__((ext_vector_type(8)));
typedef float  f32x4  __attribute__((ext_vector_type(4)));
typedef unsigned long long u64;

#define T_SEQ 512
#define NWG   128   // 8 h-cols per WG -> 32 gate rows

#define MFMA(a, b, c) __builtin_amdgcn_mfma_f32_16x16x32_bf16((a), (b), (c), 0, 0, 0)

static __device__ __forceinline__ u64 ldA8(const u64* p) {
  return __hip_atomic_load(p, __ATOMIC_RELAXED, __HIP_MEMORY_SCOPE_AGENT);
}

// ---------------- gather + convert: xe[t*64+b][512] = bf16(emb[x[b,t]]) ----------------
__global__ void gather_xe(const int* __restrict__ x, const float* __restrict__ emb,
                          bf16_t* __restrict__ xe) {
  const int row = blockIdx.x;            // row = t*64 + b
  const int b = row & 63, t = row >> 6;
  const int tok = x[b * 512 + t];        // x is [B][T]
  const float4* src = (const float4*)(emb + (size_t)tok * 512);
  float4 a = src[threadIdx.x * 2], c = src[threadIdx.x * 2 + 1];
  bf16x8 v;
  v[0] = (bf16_t)a.x; v[1] = (bf16_t)a.y; v[2] = (bf16_t)a.z; v[3] = (bf16_t)a.w;
  v[4] = (bf16_t)c.x; v[5] = (bf16_t)c.y; v[6] = (bf16_t)c.z; v[7] = (bf16_t)c.w;
  *(bf16x8*)(xe + (size_t)row * 512 + threadIdx.x * 8) = v;
}

// ---------------- persistent sequential LSTM (cooperative, fence-free) ----------------
// WG wg owns h-cols wg*8..+7 -> 32 weight rows (r = gate*8 + cl), LDS-resident bf16.
// h double-buffered in global bf16 [2][64][1024]; all h traffic via agent-scope atomics
// (write-through / cache-bypass) so NO acquire/release cache-wiping fences are needed.
// Barrier: one monotonic counter, 1 fetch_add + 1 poller lane per WG.
__global__ __launch_bounds__(256, 1) void lstm_seq(
    const bf16_t* __restrict__ xe,       // [512*64][512]
    const float* __restrict__ wih,       // [4096][512]
    const float* __restrict__ whh,       // [4096][1024]
    const float* __restrict__ bih, const float* __restrict__ bhh,
    const float* __restrict__ wfc, const float* __restrict__ bfc,
    bf16_t* __restrict__ hb,             // [2][64][1024], pre-zeroed
    unsigned int* __restrict__ cnt,      // pre-zeroed
    float* __restrict__ out) {
  __shared__ bf16_t whh_s[32][1032];     // 66,048 B (pad 8 -> bank stride 4)
  __shared__ bf16_t wih_s[32][520];      // 33,280 B
  __shared__ float gates_s[64][33];      //  8,448 B   (total ~108 KB < 160 KB)
  const int tid = threadIdx.x, wg = blockIdx.x;
  const int lane = tid & 63, w = tid >> 6;

  // ---- stage weight slices f32 -> bf16 (one-time) ----
  {
    const int r = tid >> 3, sub = tid & 7;               // 32 rows x 8 chunks
    const int grow = (r >> 3) * 1024 + wg * 8 + (r & 7); // gate*1024 + col
    const float4* s1 = (const float4*)(whh + (size_t)grow * 1024 + sub * 128);
    bf16_t* d1 = &whh_s[r][sub * 128];
#pragma unroll 8
    for (int u = 0; u < 32; ++u) {
      float4 f = s1[u];
      d1[u * 4 + 0] = (bf16_t)f.x; d1[u * 4 + 1] = (bf16_t)f.y;
      d1[u * 4 + 2] = (bf16_t)f.z; d1[u * 4 + 3] = (bf16_t)f.w;
    }
    const float4* s2 = (const float4*)(wih + (size_t)grow * 512 + sub * 64);
    bf16_t* d2 = &wih_s[r][sub * 64];
#pragma unroll 8
    for (int u = 0; u < 16; ++u) {
      float4 f = s2[u];
      d2[u * 4 + 0] = (bf16_t)f.x; d2[u * 4 + 1] = (bf16_t)f.y;
      d2[u * 4 + 2] = (bf16_t)f.z; d2[u * 4 + 3] = (bf16_t)f.w;
    }
  }

  // ---- per-thread elementwise ownership: (batch, col-pair) ----
  const int bth = tid >> 2, cp = tid & 3;
  const int cg0 = wg * 8 + cp * 2;                       // global h-col (even)
  float bias[4][2];
#pragma unroll
  for (int g = 0; g < 4; ++g) {
    bias[g][0] = bih[g * 1024 + cg0] + bhh[g * 1024 + cg0];
    bias[g][1] = bih[g * 1024 + cg0 + 1] + bhh[g * 1024 + cg0 + 1];
  }
  float c0 = 0.f, c1 = 0.f;

  const int rloc = lane & 15, kg = lane >> 4;
  const int b0 = w << 4;
  __syncthreads();

  for (int t = 0; t < T_SEQ; ++t) {
    const bf16_t* hcur = hb + (size_t)(t & 1) * 65536;
    bf16_t* hnext = hb + (size_t)((t + 1) & 1) * 65536;

    f32x4 a00 = {0.f,0.f,0.f,0.f}, a01 = a00, a10 = a00, a11 = a00;

    // ---- xe[t] @ Wih_slice^T : h-independent, runs before the barrier wait ----
    {
      const bf16_t* ar  = xe + ((size_t)t * 64 + b0 + rloc) * 512 + (kg << 3);
      const bf16_t* br0 = &wih_s[rloc][kg << 3];
      const bf16_t* br1 = &wih_s[16 + rloc][kg << 3];
#pragma unroll
      for (int kk = 0; kk < 16; kk += 2) {
        bf16x8 A0 = *(const bf16x8*)(ar + kk * 32);
        bf16x8 A1 = *(const bf16x8*)(ar + kk * 32 + 32);
        a00 = MFMA(A0, *(const bf16x8*)(br0 + kk * 32), a00);
        a10 = MFMA(A0, *(const bf16x8*)(br1 + kk * 32), a10);
        a01 = MFMA(A1, *(const bf16x8*)(br0 + kk * 32 + 32), a01);
        a11 = MFMA(A1, *(const bf16x8*)(br1 + kk * 32 + 32), a11);
      }
    }

    // ---- wait for h(t): single poller lane on one counter line ----
    if (tid == 0) {
      const unsigned int tgt = (unsigned int)t * NWG;
      while (__hip_atomic_load(cnt, __ATOMIC_RELAXED, __HIP_MEMORY_SCOPE_AGENT) < tgt)
        __builtin_amdgcn_s_sleep(2);
    }
    __syncthreads();

    // ---- h(t) @ Whh_slice^T : A-frags via coherent (L2-bypass) 8B loads ----
    {
      const u64* ap = (const u64*)(hcur + (size_t)(b0 + rloc) * 1024) + (kg << 1);
      const bf16_t* br0 = &whh_s[rloc][kg << 3];
      const bf16_t* br1 = &whh_s[16 + rloc][kg << 3];
#pragma unroll
      for (int kk = 0; kk < 32; kk += 2) {
        union { u64 u[2]; bf16x8 v; } A0, A1;
        A0.u[0] = ldA8(ap + kk * 8);     A0.u[1] = ldA8(ap + kk * 8 + 1);
        A1.u[0] = ldA8(ap + kk * 8 + 8); A1.u[1] = ldA8(ap + kk * 8 + 9);
        a00 = MFMA(A0.v, *(const bf16x8*)(br0 + kk * 32), a00);
        a10 = MFMA(A0.v, *(const bf16x8*)(br1 + kk * 32), a10);
        a01 = MFMA(A1.v, *(const bf16x8*)(br0 + kk * 32 + 32), a01);
        a11 = MFMA(A1.v, *(const bf16x8*)(br1 + kk * 32 + 32), a11);
      }
    }
    f32x4 s0 = a00 + a01, s1 = a10 + a11;
#pragma unroll
    for (int r = 0; r < 4; ++r) {
      gates_s[b0 + (kg << 2) + r][rloc] = s0[r];        // local rows 0..15 (i,f)
      gates_s[b0 + (kg << 2) + r][16 + rloc] = s1[r];   // local rows 16..31 (g,o)
    }
    __syncthreads();

    // ---- elementwise: thread (bth, cols cp*2, cp*2+1) ----
    {
      const int cl0 = cp * 2, cl1 = cl0 + 1;
      const float gi0 = gates_s[bth][cl0]      + bias[0][0];
      const float gi1 = gates_s[bth][cl1]      + bias[0][1];
      const float gf0 = gates_s[bth][8 + cl0]  + bias[1][0];
      const float gf1 = gates_s[bth][8 + cl1]  + bias[1][1];
      const float gg0 = gates_s[bth][16 + cl0] + bias[2][0];
      const float gg1 = gates_s[bth][16 + cl1] + bias[2][1];
      const float go0 = gates_s[bth][24 + cl0] + bias[3][0];
      const float go1 = gates_s[bth][24 + cl1] + bias[3][1];
      c0 = (1.f / (1.f + __expf(-gf0))) * c0 + (1.f / (1.f + __expf(-gi0))) * tanhf(gg0);
      c1 = (1.f / (1.f + __expf(-gf1))) * c1 + (1.f / (1.f + __expf(-gi1))) * tanhf(gg1);
      const float h0 = (1.f / (1.f + __expf(-go0))) * tanhf(c0);
      const float h1 = (1.f / (1.f + __expf(-go1))) * tanhf(c1);
      union { unsigned int u; bf16_t h[2]; } pk;
      pk.h[0] = (bf16_t)h0; pk.h[1] = (bf16_t)h1;
      // write-through (agent-scope) store: globally visible once vmcnt-acked
      __hip_atomic_store((unsigned int*)(hnext + (size_t)bth * 1024 + cg0), pk.u,
                         __ATOMIC_RELAXED, __HIP_MEMORY_SCOPE_AGENT);
    }
    __syncthreads();   // drains every wave's vmcnt -> all h stores globally visible

    if (tid == 0)
      __hip_atomic_fetch_add(cnt, 1u, __ATOMIC_RELAXED, __HIP_MEMORY_SCOPE_AGENT);
  }

  // ---- final FC + sigmoid on WG 0 (final h = hb[0] after 512 steps) ----
  if (wg != 0) return;
  if (tid == 0) {
    while (__hip_atomic_load(cnt, __ATOMIC_RELAXED, __HIP_MEMORY_SCOPE_AGENT) <
           (unsigned int)T_SEQ * NWG)
      __builtin_amdgcn_s_sleep(2);
  }
  __syncthreads();
  {
    const int part = tid & 3;
    const u64* hp = (const u64*)(hb + (size_t)bth * 1024 + part * 256);
    const float* wp = wfc + part * 256;
    float s = 0.f;
    for (int i = 0; i < 64; ++i) {
      union { u64 u; bf16_t h[4]; } x;
      x.u = ldA8(hp + i);
      s += (float)x.h[0] * wp[i * 4] + (float)x.h[1] * wp[i * 4 + 1] +
           (float)x.h[2] * wp[i * 4 + 2] + (float)x.h[3] * wp[i * 4 + 3];
    }
    s += __shfl_xor(s, 1);
    s += __shfl_xor(s, 2);
    if (part == 0) out[bth] = 1.f / (1.f + __expf(-(s + bfc[0])));
  }
}

extern "C" void kernel_launch(void* const* d_in, const int* in_sizes, int n_in,
                              void* d_out, int out_size, void* d_ws, size_t ws_size,
                              hipStream_t stream) {
  const int* x = (const int*)d_in[0];
  const float* emb = (const float*)d_in[1];
  const float* wih = (const float*)d_in[2];
  const float* whh = (const float*)d_in[3];
  const float* bih = (const float*)d_in[4];
  const float* bhh = (const float*)d_in[5];
  const float* wfc = (const float*)d_in[6];
  const float* bfc = (const float*)d_in[7];
  float* out = (float*)d_out;

  char* ws = (char*)d_ws;
  bf16_t* xe = (bf16_t*)ws;                              // 33,554,432 B
  bf16_t* hb = (bf16_t*)(ws + 33554432);                 //    262,144 B
  unsigned int* cnt = (unsigned int*)(ws + 33554432 + 262144);

  // zero h(0) (both buffers) + counter before the cooperative kernel
  hipMemsetAsync(hb, 0, 262144 + 64, stream);
  gather_xe<<<32768, 64, 0, stream>>>(x, emb, xe);

  void* args[] = {(void*)&xe, (void*)&wih, (void*)&whh, (void*)&bih, (void*)&bhh,
                  (void*)&wfc, (void*)&bfc, (void*)&hb, (void*)&cnt, (void*)&out};
  hipLaunchCooperativeKernel((const void*)lstm_seq, dim3(NWG), dim3(256), args, 0, stream);
}